// Round 3
// baseline (384.206 us; speedup 1.0000x reference)
//
#include <hip/hip_runtime.h>

// GCN: agg-before-GEMM on both layers (A(hW) = (Ah)W).
//   es  = bf16( dinv[i] * emb[x[i]] )               (N x 32, 3.2 MB, L2-resident)
//   L1 fused: a1(LDS) = dinv*(es[i]+sum es[src]);  hs = bf16(dinv*relu(a1@W1+b1))
//   L2 fused: agg = hs[i]+sum hs[src];  out = dinv*(agg@W2) + b2
// CSR build: bucket -> chunked-LDS-histogram counting sort (no global atomics),
// staged edges packed to one int ((dlocal<<17)|src) - halves staging traffic.
// R12 post-mortem: chunk-major per-row segments halved FETCH (151->85MB, L2
// residency works) but doubled issued gather slots (seg~16 vs batch 8 + masked
// tails + 2-group wave divergence) -> k_l2 84->151us. R14: keep chunking, go
// FLAT edge-parallel: k_reorder packs each 40-node block's edges chunk-major
// as (dlocal<<17)|src; k_l2 phase A = whole wave per edge (lane l owns cols
// l,l+64), pk loads wave-uniform (s_load), dl-runs accumulate in 2 regs and
// flush to LDS a2t via atomicAdd only on run change (edges sorted by dlocal
// within chunk). No divergence, no tails. dinv folded into phase-B epilogue.

#define NPP   6250     // nodes per partition (N=50000 / 8)
#define NC    32       // chunks per partition
#define CAP   96       // max row length handled by k_part (P(deg>96) ~ 0)
#define CAPP  97       // padded LDS stride (97 % 32 != 0 -> no bank aliasing)
#define NPB   40       // nodes per k_l2 block (1250 blocks, all co-resident)

typedef float vfloat4 __attribute__((ext_vector_type(4)));

static inline int cdiv(int a, int b){ return (a + b - 1) / b; }

__device__ __forceinline__ unsigned short f2bf(float f){
    unsigned int u = __float_as_uint(f);
    u += 0x7fffu + ((u >> 16) & 1u);          // round-to-nearest-even
    return (unsigned short)(u >> 16);
}
__device__ __forceinline__ float bf2f(unsigned short b){
    return __uint_as_float(((unsigned int)b) << 16);
}

__device__ __forceinline__ void nt_store4(float* p, const float4& v){
    vfloat4 t = {v.x, v.y, v.z, v.w};
    __builtin_nontemporal_store(t, (vfloat4*)p);
}

__global__ void k_zero_i32(int* __restrict__ p, int n){
    int i = blockIdx.x * blockDim.x + threadIdx.x;
    if (i < n) p[i] = 0;
}

// Bucket edges by dst-range into 8 staged partition arrays, packed
// (dlocal<<17)|src. LDS tiles, per-block coalesced flush (~2k gcur atomics total).
__global__ __launch_bounds__(256) void k_bucket(const int* __restrict__ src,
        const int* __restrict__ dst, int E, int* __restrict__ staged,
        int* __restrict__ gcur, int npp, int C){
    __shared__ int qcnt[8];
    __shared__ int qbase[8];
    __shared__ int qbuf[8 * 256];   // 8 KB
    int tid = threadIdx.x;
    if (tid < 8) qcnt[tid] = 0;
    __syncthreads();
    int e0 = blockIdx.x * 1024 + tid * 4;
    if (e0 + 3 < E){
        int4 d4 = *(const int4*)(dst + e0);
        int4 s4 = *(const int4*)(src + e0);
        int dd[4] = {d4.x, d4.y, d4.z, d4.w};
        int ss[4] = {s4.x, s4.y, s4.z, s4.w};
        #pragma unroll
        for (int i = 0; i < 4; i++){
            int p = dd[i] / npp;
            int pk = ((dd[i] - p * npp) << 17) | ss[i];
            int pos = atomicAdd(&qcnt[p], 1);
            if (pos < 256) qbuf[p * 256 + pos] = pk;
            else {          // statistically unreachable overflow fallback
                int gp = atomicAdd(&gcur[p], 1);
                staged[(size_t)p * C + gp] = pk;
            }
        }
    } else {
        for (int e = e0; e < E && e < e0 + 4; e++){
            int d = dst[e], s = src[e];
            int p = d / npp;
            int pk = ((d - p * npp) << 17) | s;
            int pos = atomicAdd(&qcnt[p], 1);
            if (pos < 256) qbuf[p * 256 + pos] = pk;
            else {
                int gp = atomicAdd(&gcur[p], 1);
                staged[(size_t)p * C + gp] = pk;
            }
        }
    }
    __syncthreads();
    if (tid < 8){
        int nq = min(qcnt[tid], 256);
        qbase[tid] = (nq > 0) ? atomicAdd(&gcur[tid], nq) : 0;
    }
    __syncthreads();
    for (int b = 0; b < 8; b++){
        int nq = min(qcnt[b], 256);
        int gb = qbase[b];
        for (int i = tid; i < nq; i += 256)
            staged[(size_t)b * C + gb + i] = qbuf[b * 256 + i];
    }
}

// Per-(partition,chunk) dst histogram via LDS atomics -> H[p][c][0..npp).
__global__ __launch_bounds__(256) void k_hist(const int* __restrict__ staged,
        const int* __restrict__ gcur, int C, int CH, int npp, int* __restrict__ H){
    __shared__ int hist[NPP];
    int part  = blockIdx.x & 7;
    int chunk = blockIdx.x >> 3;
    int tid = threadIdx.x;
    for (int i = tid; i < npp; i += 256) hist[i] = 0;
    __syncthreads();
    int pc = gcur[part];
    int e0 = chunk * CH, e1 = min(e0 + CH, pc);
    const int* sd = staged + (size_t)part * C;
    for (int e = e0 + tid; e < e1; e += 256)
        atomicAdd(&hist[(unsigned)sd[e] >> 17], 1);
    __syncthreads();
    int* Hrow = H + (size_t)(part * NC + chunk) * npp;
    for (int i = tid; i < npp; i += 256) Hrow[i] = hist[i];
}

// Per-node serial prefix over the NC chunk histograms: H becomes per-chunk
// exclusive base rank; ecount = total; dinv fused; per-block sums -> bsum.
__global__ __launch_bounds__(256) void k_nodescan(int* __restrict__ H, int npp, int n,
        int* __restrict__ ecount, float* __restrict__ dinv, int* __restrict__ bsum){
    __shared__ int s[256];
    int t = blockIdx.x * 256 + threadIdx.x;   // t == node id (partitions contiguous)
    int run = 0;
    if (t < 8 * npp && t < n){
        int p  = t / npp;
        int dl = t - p * npp;
        #pragma unroll
        for (int c = 0; c < NC; c++){
            size_t idx = (size_t)(p * NC + c) * npp + dl;
            int v = H[idx];
            H[idx] = run;
            run += v;
        }
        ecount[t] = run;
        dinv[t] = rsqrtf((float)run + 1.0f);   // +1 self-loop
    }
    s[threadIdx.x] = run;
    __syncthreads();
    for (int d = 128; d > 0; d >>= 1){
        if (threadIdx.x < d) s[threadIdx.x] += s[threadIdx.x + d];
        __syncthreads();
    }
    if (threadIdx.x == 0) bsum[blockIdx.x] = s[0];
}

// Fused scanB+scanC: every block re-scans the nb block sums in LDS (nb<=256),
// then does its 256-element Hillis-Steele scan -> offsets.
__global__ __launch_bounds__(256) void k_scanBC(const int* __restrict__ ecount, int n,
        const int* __restrict__ bsum, int nb, int* __restrict__ offsets){
    __shared__ int bs[256];
    __shared__ int s[256];
    int t = threadIdx.x;
    bs[t] = (t < nb) ? bsum[t] : 0;
    __syncthreads();
    if (t == 0){
        int run = 0;
        for (int b = 0; b < nb; b++){ int v = bs[b]; bs[b] = run; run += v; }
    }
    __syncthreads();
    int i = blockIdx.x * 256 + t;
    int v = (i < n) ? ecount[i] : 0;
    s[t] = v;
    __syncthreads();
    for (int d = 1; d < 256; d <<= 1){
        int x = (t >= d) ? s[t - d] : 0;
        __syncthreads();
        s[t] += x;
        __syncthreads();
    }
    if (i < n) offsets[i] = bs[blockIdx.x] + s[t] - v;
}

// Fill csr via LDS cursor preloaded with chunk base ranks. No global atomics.
__global__ __launch_bounds__(256) void k_fill3(const int* __restrict__ staged,
        const int* __restrict__ gcur, int C, int CH, int npp,
        const int* __restrict__ H, const int* __restrict__ offsets,
        int* __restrict__ csr_src){
    __shared__ int cur[NPP];
    int part  = blockIdx.x & 7;
    int chunk = blockIdx.x >> 3;
    int tid = threadIdx.x;
    const int* Hrow = H + (size_t)(part * NC + chunk) * npp;
    for (int i = tid; i < npp; i += 256) cur[i] = Hrow[i];
    __syncthreads();
    int pc = gcur[part];
    int lo = part * npp;
    int e0 = chunk * CH, e1 = min(e0 + CH, pc);
    const int* sd = staged + (size_t)part * C;
    for (int e = e0 + tid; e < e1; e += 256){
        int pk = sd[e];
        int dl = (unsigned)pk >> 17;
        int r = atomicAdd(&cur[dl], 1);
        csr_src[offsets[lo + dl] + r] = pk & 0x1FFFF;
    }
}

// 4-way partition each CSR row by src chunk (src/12500) and record the chunk
// boundaries bnd4[node] = (b1,b2,b3,cnt). Pure perf transform: rows keep the
// same multiset of sources. Fallback (cnt>CAP, statistically unreachable):
// leave row as-is and use quarter boundaries (still correct, just unaligned).
__global__ __launch_bounds__(128) void k_part(const int* __restrict__ offsets,
        const int* __restrict__ ecount, int* __restrict__ csr,
        int4* __restrict__ bnd4, int n, int th1, int th2, int th3){
    __shared__ int buf[128 * CAPP];   // 49.7 KB
    int t = threadIdx.x;
    int node = blockIdx.x * 128 + t;
    if (node >= n) return;
    int off = offsets[node], cnt = ecount[node];
    int4 b;
    if (cnt <= CAP){
        int* mb = buf + t * CAPP;
        int c0 = 0, c1 = 0, c2 = 0;
        for (int i = 0; i < cnt; i++){
            int v = csr[off + i];
            mb[i] = v;
            c0 += (v < th1);
            c1 += (v >= th1) & (v < th2);
            c2 += (v >= th2) & (v < th3);
        }
        int p1 = c0, p2 = c0 + c1, p3 = c0 + c1 + c2;
        int q0 = 0, q1 = p1, q2 = p2, q3 = p3;
        for (int i = 0; i < cnt; i++){
            int v = mb[i];
            int pos;
            if      (v < th1) pos = q0++;
            else if (v < th2) pos = q1++;
            else if (v < th3) pos = q2++;
            else              pos = q3++;
            csr[off + pos] = v;
        }
        b = make_int4(p1, p2, p3, cnt);
    } else {
        int q = cnt >> 2;
        b = make_int4(q, 2 * q, 3 * q, cnt);
    }
    bnd4[node] = b;
}

// Reorder each 40-node l2-block's edge span chunk-major, packing (dlocal<<17)|src.
// Output csr2 within [offsets[b*40], offsets[b*40+40]) holds chunk-0 segments of
// all 40 rows (row-ascending), then chunk-1, ... cb4[b] = relative chunk ends.
__global__ __launch_bounds__(256) void k_reorder(const int* __restrict__ offsets,
        const int4* __restrict__ bnd4, const int* __restrict__ csr,
        int* __restrict__ csr2, int4* __restrict__ cb4, int n){
    __shared__ int segl[4][NPB];
    __shared__ int base[4][NPB];
    __shared__ int cend[4];
    int b = blockIdx.x;
    int n0 = b * NPB;
    if (n0 >= n) return;
    int tid = threadIdx.x;
    if (tid < 4 * NPB){
        int c  = tid / NPB;
        int nl = tid - c * NPB;
        int node = n0 + nl;
        int4 bd = (node < n) ? bnd4[node] : make_int4(0, 0, 0, 0);
        int s = (c == 0) ? bd.x : (c == 1) ? bd.y - bd.x
              : (c == 2) ? bd.z - bd.y : bd.w - bd.z;
        segl[c][nl] = s;
    }
    __syncthreads();
    if (tid == 0){
        int run = 0;
        for (int c = 0; c < 4; c++){
            for (int nl = 0; nl < NPB; nl++){ base[c][nl] = run; run += segl[c][nl]; }
            cend[c] = run;
        }
        cb4[b] = make_int4(cend[0], cend[1], cend[2], cend[3]);
    }
    __syncthreads();
    int bb = offsets[n0];
    int g = tid >> 5, lane = tid & 31;
    for (int j = 0; j < 5; j++){
        int nl = g + 8 * j;
        int node = n0 + nl;
        if (node >= n) continue;
        int off = offsets[node];
        int4 bd = bnd4[node];
        #pragma unroll
        for (int c = 0; c < 4; c++){
            int s0 = (c == 0) ? 0    : (c == 1) ? bd.x : (c == 2) ? bd.y : bd.z;
            int s1 = (c == 0) ? bd.x : (c == 1) ? bd.y : (c == 2) ? bd.z : bd.w;
            int len = s1 - s0;
            int dstb = bb + base[c][nl];
            for (int i = lane; i < len; i += 32)
                csr2[dstb + i] = (nl << 17) | csr[off + s0 + i];
        }
    }
}

// es[i][c] = bf16( emb[x[i]][c] * dinv[i] )
__global__ void k_scale(const float* __restrict__ emb, const int* __restrict__ x,
                        const float* __restrict__ dinv, unsigned short* __restrict__ es, int n){
    int idx = blockIdx.x * blockDim.x + threadIdx.x;
    if (idx >= n * 32) return;
    int i = idx >> 5;
    int c = idx & 31;
    es[idx] = f2bf(emb[(size_t)x[i] * 32 + c] * dinv[i]);
}

// Layer 1 fused (R10 form): gather(32-dim es) -> LDS a1 tile -> GEMM W1 -> hs.
// es is 3.2 MB -> fits any single XCD L2; no chunking needed here.
__global__ __launch_bounds__(256) void k_l1(const unsigned short* __restrict__ es,
        const int* __restrict__ offsets, const int* __restrict__ ecount,
        const int* __restrict__ csr, const float* __restrict__ dinv,
        const float* __restrict__ W1, const float* __restrict__ b1,
        unsigned short* __restrict__ hs, int n){
    __shared__ float w[32 * 128];     // 16 KB
    __shared__ float a1t[8][32];      // 1 KB
    for (int i = threadIdx.x; i < 32 * 128; i += 256) w[i] = W1[i];
    int g    = threadIdx.x >> 5;
    int lane = threadIdx.x & 31;
    int node = blockIdx.x * 8 + g;
    // --- phase A: aggregate into LDS ---
    if (node < n){
        int off = offsets[node], cnt = ecount[node];
        float s0 = bf2f(es[(size_t)node * 32 + lane]);   // self-loop term
        float s1 = 0.f;
        int e = 0;
        for (; e + 8 <= cnt; e += 8){
            int i0 = csr[off + e + 0], i1 = csr[off + e + 1];
            int i2 = csr[off + e + 2], i3 = csr[off + e + 3];
            int i4 = csr[off + e + 4], i5 = csr[off + e + 5];
            int i6 = csr[off + e + 6], i7 = csr[off + e + 7];
            unsigned short v0 = es[(size_t)i0 * 32 + lane];
            unsigned short v1 = es[(size_t)i1 * 32 + lane];
            unsigned short v2 = es[(size_t)i2 * 32 + lane];
            unsigned short v3 = es[(size_t)i3 * 32 + lane];
            unsigned short v4 = es[(size_t)i4 * 32 + lane];
            unsigned short v5 = es[(size_t)i5 * 32 + lane];
            unsigned short v6 = es[(size_t)i6 * 32 + lane];
            unsigned short v7 = es[(size_t)i7 * 32 + lane];
            s0 += bf2f(v0) + bf2f(v2) + bf2f(v4) + bf2f(v6);
            s1 += bf2f(v1) + bf2f(v3) + bf2f(v5) + bf2f(v7);
        }
        for (; e < cnt; e++) s0 += bf2f(es[(size_t)csr[off + e] * 32 + lane]);
        a1t[g][lane] = dinv[node] * (s0 + s1);
    }
    __syncthreads();
    // --- phase B: hs[node] = bf16(dinv * relu(a1 @ W1 + b1)) ---
    if (node >= n) return;
    int c4 = lane * 4;
    float4 acc = *(const float4*)(b1 + c4);
    #pragma unroll
    for (int k4 = 0; k4 < 8; k4++){
        float4 av = *(const float4*)&a1t[g][k4 * 4];
        float4 w0 = *(const float4*)&w[(k4 * 4 + 0) * 128 + c4];
        float4 w1 = *(const float4*)&w[(k4 * 4 + 1) * 128 + c4];
        float4 w2 = *(const float4*)&w[(k4 * 4 + 2) * 128 + c4];
        float4 w3 = *(const float4*)&w[(k4 * 4 + 3) * 128 + c4];
        acc.x += av.x * w0.x + av.y * w1.x + av.z * w2.x + av.w * w3.x;
        acc.y += av.x * w0.y + av.y * w1.y + av.z * w2.y + av.w * w3.y;
        acc.z += av.x * w0.z + av.y * w1.z + av.z * w2.z + av.w * w3.z;
        acc.w += av.x * w0.w + av.y * w1.w + av.z * w2.w + av.w * w3.w;
    }
    float dv = dinv[node];
    ushort4 o;
    o.x = f2bf(dv * fmaxf(acc.x, 0.f));
    o.y = f2bf(dv * fmaxf(acc.y, 0.f));
    o.z = f2bf(dv * fmaxf(acc.z, 0.f));
    o.w = f2bf(dv * fmaxf(acc.w, 0.f));
    *(ushort4*)(hs + (size_t)node * 128 + c4) = o;
}

// Layer 2 fused, flat edge-parallel chunk-major (R14). 40 nodes/block, 1250
// blocks, all co-resident (launch_bounds(256,5), LDS 20.5KB). Phase A: whole
// wave per edge run; lane l owns cols (l, l+64); pk loads wave-uniform
// (s_load); dl-run accumulation in 2 regs, LDS atomicAdd flush on run change
// (2-way bank = free). Phase B: 5 rows x 4 cols/thread, dinv in epilogue.
__global__ __launch_bounds__(256, 5) void k_l2(const unsigned short* __restrict__ hs,
        const int* __restrict__ offsets, const int4* __restrict__ cb4,
        const int* __restrict__ csr2, const float* __restrict__ dinv,
        const float* __restrict__ W2, const float* __restrict__ b2,
        float* __restrict__ out, int n){
    __shared__ float a2t[NPB * 128];   // 20.5 KB
    int tid = threadIdx.x;
    int b   = blockIdx.x;
    int n0  = b * NPB;
    // --- init a2t with self rows (bf16 pair -> 2 floats per dword) ---
    for (int idx = tid; idx < NPB * 64; idx += 256){
        int nl = idx >> 6, h = idx & 63;
        int node = n0 + nl;
        float lo = 0.f, hi = 0.f;
        if (node < n){
            unsigned int u = *(const unsigned int*)(hs + (size_t)node * 128 + 2 * h);
            lo = __uint_as_float(u << 16);
            hi = __uint_as_float(u & 0xFFFF0000u);
        }
        a2t[nl * 128 + 2 * h]     = lo;
        a2t[nl * 128 + 2 * h + 1] = hi;
    }
    __syncthreads();
    // --- phase A: flat edge loop, 4 waves shard each chunk span ---
    int lane = tid & 63;
    int wid  = __builtin_amdgcn_readfirstlane(tid >> 6);   // wave-uniform
    int bb = offsets[n0];
    int4 cb = cb4[b];
    const int* cp = csr2 + bb;
    #pragma unroll
    for (int c = 0; c < 4; c++){
        int s  = (c == 0) ? 0    : (c == 1) ? cb.x : (c == 2) ? cb.y : cb.z;
        int t1 = (c == 0) ? cb.x : (c == 1) ? cb.y : (c == 2) ? cb.z : cb.w;
        int len = t1 - s;
        int ws = (len + 3) >> 2;
        int e0 = s + wid * ws;
        int e1 = min(e0 + ws, t1);
        float f0 = 0.f, f1 = 0.f;
        int cur = -1;
        int e = e0;
        for (; e + 8 <= e1; e += 8){
            int pk0 = cp[e + 0], pk1 = cp[e + 1], pk2 = cp[e + 2], pk3 = cp[e + 3];
            int pk4 = cp[e + 4], pk5 = cp[e + 5], pk6 = cp[e + 6], pk7 = cp[e + 7];
            const unsigned short* h0 = hs + (size_t)(pk0 & 0x1FFFF) * 128;
            const unsigned short* h1 = hs + (size_t)(pk1 & 0x1FFFF) * 128;
            const unsigned short* h2 = hs + (size_t)(pk2 & 0x1FFFF) * 128;
            const unsigned short* h3 = hs + (size_t)(pk3 & 0x1FFFF) * 128;
            const unsigned short* h4 = hs + (size_t)(pk4 & 0x1FFFF) * 128;
            const unsigned short* h5 = hs + (size_t)(pk5 & 0x1FFFF) * 128;
            const unsigned short* h6 = hs + (size_t)(pk6 & 0x1FFFF) * 128;
            const unsigned short* h7 = hs + (size_t)(pk7 & 0x1FFFF) * 128;
            unsigned int a0 = h0[lane], b0 = h0[lane + 64];
            unsigned int a1 = h1[lane], b1v = h1[lane + 64];
            unsigned int a2 = h2[lane], b2v = h2[lane + 64];
            unsigned int a3 = h3[lane], b3v = h3[lane + 64];
            unsigned int a4 = h4[lane], b4v = h4[lane + 64];
            unsigned int a5 = h5[lane], b5v = h5[lane + 64];
            unsigned int a6 = h6[lane], b6v = h6[lane + 64];
            unsigned int a7 = h7[lane], b7v = h7[lane + 64];
            int pks[8] = {pk0, pk1, pk2, pk3, pk4, pk5, pk6, pk7};
            unsigned int as[8] = {a0, a1, a2, a3, a4, a5, a6, a7};
            unsigned int bs[8] = {b0, b1v, b2v, b3v, b4v, b5v, b6v, b7v};
            #pragma unroll
            for (int i = 0; i < 8; i++){
                int dl = pks[i] >> 17;
                if (dl != cur){
                    if (cur >= 0){
                        atomicAdd(&a2t[cur * 128 + lane], f0);
                        atomicAdd(&a2t[cur * 128 + 64 + lane], f1);
                    }
                    cur = dl; f0 = 0.f; f1 = 0.f;
                }
                f0 += __uint_as_float(as[i] << 16);
                f1 += __uint_as_float(bs[i] << 16);
            }
        }
        for (; e < e1; e++){
            int pk = cp[e];
            const unsigned short* hp = hs + (size_t)(pk & 0x1FFFF) * 128;
            unsigned int u0 = hp[lane], u1 = hp[lane + 64];
            int dl = pk >> 17;
            if (dl != cur){
                if (cur >= 0){
                    atomicAdd(&a2t[cur * 128 + lane], f0);
                    atomicAdd(&a2t[cur * 128 + 64 + lane], f1);
                }
                cur = dl; f0 = 0.f; f1 = 0.f;
            }
            f0 += __uint_as_float(u0 << 16);
            f1 += __uint_as_float(u1 << 16);
        }
        if (cur >= 0){
            atomicAdd(&a2t[cur * 128 + lane], f0);
            atomicAdd(&a2t[cur * 128 + 64 + lane], f1);
        }
    }
    __syncthreads();
    // --- phase B: out[r] = dinv[r]*(a2t[r] @ W2) + b2 ; 5 rows x 4 cols ---
    int g = tid >> 5, l32 = tid & 31;
    int c4 = l32 * 4;
    int r0 = g * 5;
    float4 o0 = {0,0,0,0}, o1 = {0,0,0,0}, o2 = {0,0,0,0}, o3 = {0,0,0,0}, o4 = {0,0,0,0};
    for (int k = 0; k < 128; k += 4){
        float4 a0 = *(const float4*)&a2t[(r0 + 0) * 128 + k];
        float4 a1v= *(const float4*)&a2t[(r0 + 1) * 128 + k];
        float4 a2v= *(const float4*)&a2t[(r0 + 2) * 128 + k];
        float4 a3v= *(const float4*)&a2t[(r0 + 3) * 128 + k];
        float4 a4v= *(const float4*)&a2t[(r0 + 4) * 128 + k];
        #pragma unroll
        for (int kk = 0; kk < 4; kk++){
            float4 wv = *(const float4*)(W2 + (size_t)(k + kk) * 128 + c4);
            float b0 = (kk == 0) ? a0.x  : (kk == 1) ? a0.y  : (kk == 2) ? a0.z  : a0.w;
            float b1v= (kk == 0) ? a1v.x : (kk == 1) ? a1v.y : (kk == 2) ? a1v.z : a1v.w;
            float b2v= (kk == 0) ? a2v.x : (kk == 1) ? a2v.y : (kk == 2) ? a2v.z : a2v.w;
            float b3 = (kk == 0) ? a3v.x : (kk == 1) ? a3v.y : (kk == 2) ? a3v.z : a3v.w;
            float b4 = (kk == 0) ? a4v.x : (kk == 1) ? a4v.y : (kk == 2) ? a4v.z : a4v.w;
            o0.x += b0 * wv.x; o0.y += b0 * wv.y; o0.z += b0 * wv.z; o0.w += b0 * wv.w;
            o1.x += b1v * wv.x; o1.y += b1v * wv.y; o1.z += b1v * wv.z; o1.w += b1v * wv.w;
            o2.x += b2v * wv.x; o2.y += b2v * wv.y; o2.z += b2v * wv.z; o2.w += b2v * wv.w;
            o3.x += b3 * wv.x; o3.y += b3 * wv.y; o3.z += b3 * wv.z; o3.w += b3 * wv.w;
            o4.x += b4 * wv.x; o4.y += b4 * wv.y; o4.z += b4 * wv.z; o4.w += b4 * wv.w;
        }
    }
    int rb = n0 + r0;
    float4 bias = *(const float4*)(b2 + c4);
    #pragma unroll
    for (int i = 0; i < 5; i++){
        int r = rb + i;
        if (r < n){
            float dv = dinv[r];
            float4 oi = (i == 0) ? o0 : (i == 1) ? o1 : (i == 2) ? o2 : (i == 3) ? o3 : o4;
            float4 res;
            res.x = bias.x + dv * oi.x;
            res.y = bias.y + dv * oi.y;
            res.z = bias.z + dv * oi.z;
            res.w = bias.w + dv * oi.w;
            nt_store4(out + (size_t)r * 128 + c4, res);
        }
    }
}

extern "C" void kernel_launch(void* const* d_in, const int* in_sizes, int n_in,
                              void* d_out, int out_size, void* d_ws, size_t ws_size,
                              hipStream_t stream){
    const int*   x    = (const int*)d_in[0];
    const int*   ei   = (const int*)d_in[1];
    const float* emb  = (const float*)d_in[2];
    const float* W1   = (const float*)d_in[3];
    const float* b1   = (const float*)d_in[4];
    const float* W2   = (const float*)d_in[5];
    const float* b2   = (const float*)d_in[6];
    const int N = in_sizes[0];
    const int E = in_sizes[1] / 2;
    const int* srcv = ei;
    const int* dstv = ei + E;
    float* out = (float*)d_out;

    char* p = (char*)d_ws;
    auto alloc = [&](size_t bytes) -> char* {
        char* r = p; p += (bytes + 255) & ~(size_t)255; return r;
    };
    int nb = cdiv(N, 256);
    int nblk2 = cdiv(N, NPB);
    int*            ecount  = (int*)           alloc((size_t)(N + 8) * 4); // +8: gcur
    int*            gcur    = ecount + N;
    int*            offsets = (int*)           alloc((size_t)N * 4);
    int*            bsum    = (int*)           alloc((size_t)nb * 4);
    float*          dinv    = (float*)         alloc((size_t)N * 4);
    int*            csr     = (int*)           alloc((size_t)E * 4);
    int*            csr2    = (int*)           alloc((size_t)E * 4);
    int4*           cb4     = (int4*)          alloc((size_t)nblk2 * 16);
    unsigned short* es      = (unsigned short*)alloc((size_t)N * 32 * 2);
    int*            H       = (int*)           alloc((size_t)8 * NC * NPP * 4); // 6.4 MB
    unsigned short* hs      = (unsigned short*)alloc((size_t)N * 128 * 2);
    int4*           bnd4    = (int4*)          alloc((size_t)N * 16);
    int*            staged  = (int*)           alloc((size_t)(E + 8 * 65536) * 4);
    (void)ws_size; (void)n_in; (void)out_size;

    const int npp = cdiv(N, 8);          // nodes per partition (== NPP for N=50000)
    const int C   = E / 8 + 65536;       // staged capacity per partition
    const int CH  = cdiv(C, NC);         // edges per chunk
    const int th1 = cdiv(N, 4), th2 = 2 * th1, th3 = 3 * th1;  // src chunk bounds

    // --- CSR build (no global atomics on hot path) ---
    k_zero_i32<<<1, 64, 0, stream>>>(gcur, 8);
    k_bucket  <<<cdiv(E, 1024), 256, 0, stream>>>(srcv, dstv, E, staged, gcur, npp, C);
    k_hist    <<<8 * NC, 256, 0, stream>>>(staged, gcur, C, CH, npp, H);
    k_nodescan<<<nb, 256, 0, stream>>>(H, npp, N, ecount, dinv, bsum);
    k_scanBC  <<<nb, 256, 0, stream>>>(ecount, N, bsum, nb, offsets);
    k_fill3   <<<8 * NC, 256, 0, stream>>>(staged, gcur, C, CH, npp, H, offsets, csr);
    k_part    <<<cdiv(N, 128), 128, 0, stream>>>(offsets, ecount, csr, bnd4, N, th1, th2, th3);
    k_reorder <<<nblk2, 256, 0, stream>>>(offsets, bnd4, csr, csr2, cb4, N);

    // --- layer 1 (fused): scale -> [gather+GEMM] -> hs ---
    k_scale <<<cdiv(N * 32, 256), 256, 0, stream>>>(emb, x, dinv, es, N);
    k_l1    <<<cdiv(N, 8), 256, 0, stream>>>(es, offsets, ecount, csr, dinv, W1, b1, hs, N);

    // --- layer 2 (fused, flat edge-parallel): [gather+GEMM] -> out ---
    k_l2    <<<nblk2, 256, 0, stream>>>(hs, offsets, cb4, csr2, dinv, W2, b2, out, N);
}

// Round 4
// 285.251 us; speedup vs baseline: 1.3469x; 1.3469x over previous
//
#include <hip/hip_runtime.h>

// GCN: agg-before-GEMM on both layers (A(hW) = (Ah)W).
//   es  = bf16( dinv[i] * emb[x[i]] )               (N x 32, 3.2 MB, L2-resident)
//   L1 fused: a1(LDS) = dinv*(es[i]+sum es[src]);  hs = bf16(dinv*relu(a1@W1+b1))
//   L2 fused: a2(LDS) = dinv*(hs[i]+sum hs[src]);  out = a2@W2 + b2
// CSR build: bucket -> chunked-LDS-histogram counting sort (no global atomics).
// R12/R14 post-mortem: both chunk-for-L2-residency schemes (per-row segments,
// flat edge-parallel) regressed k_l2 (84 -> 151 / 170us). FETCH evidence says
// every XCD must stream ~all of hs regardless (compulsory ~100MB); the
// restructuring cost more issue efficiency than residency saved in latency.
// R15: revert to proven R10 form; attack the latency-exposure chain instead:
// unroll gather loops to 16 with all idx loads + all gathers issued before
// accumulation (2x memory-level parallelism), in both k_l1 and k_l2.
// k_part/k_reorder dropped.

#define NPP   6250     // nodes per partition (N=50000 / 8)
#define NC    32       // chunks per partition

typedef float vfloat4 __attribute__((ext_vector_type(4)));

static inline int cdiv(int a, int b){ return (a + b - 1) / b; }

__device__ __forceinline__ unsigned short f2bf(float f){
    unsigned int u = __float_as_uint(f);
    u += 0x7fffu + ((u >> 16) & 1u);          // round-to-nearest-even
    return (unsigned short)(u >> 16);
}
__device__ __forceinline__ float bf2f(unsigned short b){
    return __uint_as_float(((unsigned int)b) << 16);
}

__device__ __forceinline__ void nt_store4(float* p, const float4& v){
    vfloat4 t = {v.x, v.y, v.z, v.w};
    __builtin_nontemporal_store(t, (vfloat4*)p);
}

__global__ void k_zero_i32(int* __restrict__ p, int n){
    int i = blockIdx.x * blockDim.x + threadIdx.x;
    if (i < n) p[i] = 0;
}

// Bucket edges by dst-range into 8 staged partition arrays, packed
// (dlocal<<17)|src. LDS tiles, per-block coalesced flush (~2k gcur atomics total).
__global__ __launch_bounds__(256) void k_bucket(const int* __restrict__ src,
        const int* __restrict__ dst, int E, int* __restrict__ staged,
        int* __restrict__ gcur, int npp, int C){
    __shared__ int qcnt[8];
    __shared__ int qbase[8];
    __shared__ int qbuf[8 * 256];   // 8 KB
    int tid = threadIdx.x;
    if (tid < 8) qcnt[tid] = 0;
    __syncthreads();
    int e0 = blockIdx.x * 1024 + tid * 4;
    if (e0 + 3 < E){
        int4 d4 = *(const int4*)(dst + e0);
        int4 s4 = *(const int4*)(src + e0);
        int dd[4] = {d4.x, d4.y, d4.z, d4.w};
        int ss[4] = {s4.x, s4.y, s4.z, s4.w};
        #pragma unroll
        for (int i = 0; i < 4; i++){
            int p = dd[i] / npp;
            int pk = ((dd[i] - p * npp) << 17) | ss[i];
            int pos = atomicAdd(&qcnt[p], 1);
            if (pos < 256) qbuf[p * 256 + pos] = pk;
            else {          // statistically unreachable overflow fallback
                int gp = atomicAdd(&gcur[p], 1);
                staged[(size_t)p * C + gp] = pk;
            }
        }
    } else {
        for (int e = e0; e < E && e < e0 + 4; e++){
            int d = dst[e], s = src[e];
            int p = d / npp;
            int pk = ((d - p * npp) << 17) | s;
            int pos = atomicAdd(&qcnt[p], 1);
            if (pos < 256) qbuf[p * 256 + pos] = pk;
            else {
                int gp = atomicAdd(&gcur[p], 1);
                staged[(size_t)p * C + gp] = pk;
            }
        }
    }
    __syncthreads();
    if (tid < 8){
        int nq = min(qcnt[tid], 256);
        qbase[tid] = (nq > 0) ? atomicAdd(&gcur[tid], nq) : 0;
    }
    __syncthreads();
    for (int b = 0; b < 8; b++){
        int nq = min(qcnt[b], 256);
        int gb = qbase[b];
        for (int i = tid; i < nq; i += 256)
            staged[(size_t)b * C + gb + i] = qbuf[b * 256 + i];
    }
}

// Per-(partition,chunk) dst histogram via LDS atomics -> H[p][c][0..npp).
__global__ __launch_bounds__(256) void k_hist(const int* __restrict__ staged,
        const int* __restrict__ gcur, int C, int CH, int npp, int* __restrict__ H){
    __shared__ int hist[NPP];
    int part  = blockIdx.x & 7;
    int chunk = blockIdx.x >> 3;
    int tid = threadIdx.x;
    for (int i = tid; i < npp; i += 256) hist[i] = 0;
    __syncthreads();
    int pc = gcur[part];
    int e0 = chunk * CH, e1 = min(e0 + CH, pc);
    const int* sd = staged + (size_t)part * C;
    for (int e = e0 + tid; e < e1; e += 256)
        atomicAdd(&hist[(unsigned)sd[e] >> 17], 1);
    __syncthreads();
    int* Hrow = H + (size_t)(part * NC + chunk) * npp;
    for (int i = tid; i < npp; i += 256) Hrow[i] = hist[i];
}

// Per-node serial prefix over the NC chunk histograms: H becomes per-chunk
// exclusive base rank; ecount = total; dinv fused; per-block sums -> bsum.
__global__ __launch_bounds__(256) void k_nodescan(int* __restrict__ H, int npp, int n,
        int* __restrict__ ecount, float* __restrict__ dinv, int* __restrict__ bsum){
    __shared__ int s[256];
    int t = blockIdx.x * 256 + threadIdx.x;   // t == node id (partitions contiguous)
    int run = 0;
    if (t < 8 * npp && t < n){
        int p  = t / npp;
        int dl = t - p * npp;
        #pragma unroll
        for (int c = 0; c < NC; c++){
            size_t idx = (size_t)(p * NC + c) * npp + dl;
            int v = H[idx];
            H[idx] = run;
            run += v;
        }
        ecount[t] = run;
        dinv[t] = rsqrtf((float)run + 1.0f);   // +1 self-loop
    }
    s[threadIdx.x] = run;
    __syncthreads();
    for (int d = 128; d > 0; d >>= 1){
        if (threadIdx.x < d) s[threadIdx.x] += s[threadIdx.x + d];
        __syncthreads();
    }
    if (threadIdx.x == 0) bsum[blockIdx.x] = s[0];
}

// Fused scanB+scanC: every block re-scans the nb block sums in LDS (nb<=256),
// then does its 256-element Hillis-Steele scan -> offsets.
__global__ __launch_bounds__(256) void k_scanBC(const int* __restrict__ ecount, int n,
        const int* __restrict__ bsum, int nb, int* __restrict__ offsets){
    __shared__ int bs[256];
    __shared__ int s[256];
    int t = threadIdx.x;
    bs[t] = (t < nb) ? bsum[t] : 0;
    __syncthreads();
    if (t == 0){
        int run = 0;
        for (int b = 0; b < nb; b++){ int v = bs[b]; bs[b] = run; run += v; }
    }
    __syncthreads();
    int i = blockIdx.x * 256 + t;
    int v = (i < n) ? ecount[i] : 0;
    s[t] = v;
    __syncthreads();
    for (int d = 1; d < 256; d <<= 1){
        int x = (t >= d) ? s[t - d] : 0;
        __syncthreads();
        s[t] += x;
        __syncthreads();
    }
    if (i < n) offsets[i] = bs[blockIdx.x] + s[t] - v;
}

// Fill csr via LDS cursor preloaded with chunk base ranks. No global atomics.
__global__ __launch_bounds__(256) void k_fill3(const int* __restrict__ staged,
        const int* __restrict__ gcur, int C, int CH, int npp,
        const int* __restrict__ H, const int* __restrict__ offsets,
        int* __restrict__ csr_src){
    __shared__ int cur[NPP];
    int part  = blockIdx.x & 7;
    int chunk = blockIdx.x >> 3;
    int tid = threadIdx.x;
    const int* Hrow = H + (size_t)(part * NC + chunk) * npp;
    for (int i = tid; i < npp; i += 256) cur[i] = Hrow[i];
    __syncthreads();
    int pc = gcur[part];
    int lo = part * npp;
    int e0 = chunk * CH, e1 = min(e0 + CH, pc);
    const int* sd = staged + (size_t)part * C;
    for (int e = e0 + tid; e < e1; e += 256){
        int pk = sd[e];
        int dl = (unsigned)pk >> 17;
        int r = atomicAdd(&cur[dl], 1);
        csr_src[offsets[lo + dl] + r] = pk & 0x1FFFF;
    }
}

// es[i][c] = bf16( emb[x[i]][c] * dinv[i] )
__global__ void k_scale(const float* __restrict__ emb, const int* __restrict__ x,
                        const float* __restrict__ dinv, unsigned short* __restrict__ es, int n){
    int idx = blockIdx.x * blockDim.x + threadIdx.x;
    if (idx >= n * 32) return;
    int i = idx >> 5;
    int c = idx & 31;
    es[idx] = f2bf(emb[(size_t)x[i] * 32 + c] * dinv[i]);
}

// Layer 1 fused: gather(32-dim es) -> LDS a1 tile -> GEMM W1 -> hs.
// 8 nodes/block; phase A: 32 lanes/node, unroll 16 (all idx + all gathers
// issued before accumulation -> 16 loads in flight per group).
__global__ __launch_bounds__(256) void k_l1(const unsigned short* __restrict__ es,
        const int* __restrict__ offsets, const int* __restrict__ ecount,
        const int* __restrict__ csr, const float* __restrict__ dinv,
        const float* __restrict__ W1, const float* __restrict__ b1,
        unsigned short* __restrict__ hs, int n){
    __shared__ float w[32 * 128];     // 16 KB
    __shared__ float a1t[8][32];      // 1 KB
    for (int i = threadIdx.x; i < 32 * 128; i += 256) w[i] = W1[i];
    int g    = threadIdx.x >> 5;
    int lane = threadIdx.x & 31;
    int node = blockIdx.x * 8 + g;
    // --- phase A: aggregate into LDS ---
    if (node < n){
        int off = offsets[node], cnt = ecount[node];
        float s0 = bf2f(es[(size_t)node * 32 + lane]);   // self-loop term
        float s1 = 0.f;
        int e = 0;
        for (; e + 16 <= cnt; e += 16){
            int idx[16];
            #pragma unroll
            for (int i = 0; i < 16; i++) idx[i] = csr[off + e + i];
            unsigned short v[16];
            #pragma unroll
            for (int i = 0; i < 16; i++) v[i] = es[(size_t)idx[i] * 32 + lane];
            #pragma unroll
            for (int i = 0; i < 16; i += 2){
                s0 += bf2f(v[i]);
                s1 += bf2f(v[i + 1]);
            }
        }
        for (; e + 8 <= cnt; e += 8){
            int idx[8];
            #pragma unroll
            for (int i = 0; i < 8; i++) idx[i] = csr[off + e + i];
            unsigned short v[8];
            #pragma unroll
            for (int i = 0; i < 8; i++) v[i] = es[(size_t)idx[i] * 32 + lane];
            #pragma unroll
            for (int i = 0; i < 8; i += 2){
                s0 += bf2f(v[i]);
                s1 += bf2f(v[i + 1]);
            }
        }
        for (; e < cnt; e++) s0 += bf2f(es[(size_t)csr[off + e] * 32 + lane]);
        a1t[g][lane] = dinv[node] * (s0 + s1);
    }
    __syncthreads();
    // --- phase B: hs[node] = bf16(dinv * relu(a1 @ W1 + b1)) ---
    if (node >= n) return;
    int c4 = lane * 4;
    float4 acc = *(const float4*)(b1 + c4);
    #pragma unroll
    for (int k4 = 0; k4 < 8; k4++){
        float4 av = *(const float4*)&a1t[g][k4 * 4];
        float4 w0 = *(const float4*)&w[(k4 * 4 + 0) * 128 + c4];
        float4 w1 = *(const float4*)&w[(k4 * 4 + 1) * 128 + c4];
        float4 w2 = *(const float4*)&w[(k4 * 4 + 2) * 128 + c4];
        float4 w3 = *(const float4*)&w[(k4 * 4 + 3) * 128 + c4];
        acc.x += av.x * w0.x + av.y * w1.x + av.z * w2.x + av.w * w3.x;
        acc.y += av.x * w0.y + av.y * w1.y + av.z * w2.y + av.w * w3.y;
        acc.z += av.x * w0.z + av.y * w1.z + av.z * w2.z + av.w * w3.z;
        acc.w += av.x * w0.w + av.y * w1.w + av.z * w2.w + av.w * w3.w;
    }
    float dv = dinv[node];
    ushort4 o;
    o.x = f2bf(dv * fmaxf(acc.x, 0.f));
    o.y = f2bf(dv * fmaxf(acc.y, 0.f));
    o.z = f2bf(dv * fmaxf(acc.z, 0.f));
    o.w = f2bf(dv * fmaxf(acc.w, 0.f));
    *(ushort4*)(hs + (size_t)node * 128 + c4) = o;
}

// Layer 2 fused (R10 form + unroll 16): gather(128-dim hs) -> LDS a2 tile
// (16 KB) -> GEMM W2. 32 nodes/block; phase A: 8 groups x 32 lanes, 4
// nodes/group, ushort4, unroll 16 (16 gathers in flight); phase B: thread =
// 4 rows x 4 cols, W2 from global (64 KB, L1/L2-resident).
__global__ __launch_bounds__(256, 5) void k_l2(const unsigned short* __restrict__ hs,
        const int* __restrict__ offsets, const int* __restrict__ ecount,
        const int* __restrict__ csr, const float* __restrict__ dinv,
        const float* __restrict__ W2, const float* __restrict__ b2,
        float* __restrict__ out, int n){
    __shared__ float a2t[32 * 128];   // 16 KB
    int g    = threadIdx.x >> 5;
    int lane = threadIdx.x & 31;
    int c4g  = lane * 4;
    // --- phase A: aggregate 4 nodes per 32-lane group ---
    #pragma unroll
    for (int j = 0; j < 4; j++){
        int nl = g + 8 * j;
        int node = blockIdx.x * 32 + nl;
        if (node < n){
            int off = offsets[node], cnt = ecount[node];
            ushort4 sv = *(const ushort4*)(hs + (size_t)node * 128 + c4g);
            float ax0 = bf2f(sv.x), ax1 = 0.f;
            float ay0 = bf2f(sv.y), ay1 = 0.f;
            float az0 = bf2f(sv.z), az1 = 0.f;
            float aw0 = bf2f(sv.w), aw1 = 0.f;
            int e = 0;
            for (; e + 16 <= cnt; e += 16){
                int idx[16];
                #pragma unroll
                for (int i = 0; i < 16; i++) idx[i] = csr[off + e + i];
                ushort4 v[16];
                #pragma unroll
                for (int i = 0; i < 16; i++)
                    v[i] = *(const ushort4*)(hs + (size_t)idx[i] * 128 + c4g);
                #pragma unroll
                for (int i = 0; i < 16; i += 2){
                    ax0 += bf2f(v[i].x); ax1 += bf2f(v[i + 1].x);
                    ay0 += bf2f(v[i].y); ay1 += bf2f(v[i + 1].y);
                    az0 += bf2f(v[i].z); az1 += bf2f(v[i + 1].z);
                    aw0 += bf2f(v[i].w); aw1 += bf2f(v[i + 1].w);
                }
            }
            for (; e + 8 <= cnt; e += 8){
                int idx[8];
                #pragma unroll
                for (int i = 0; i < 8; i++) idx[i] = csr[off + e + i];
                ushort4 v[8];
                #pragma unroll
                for (int i = 0; i < 8; i++)
                    v[i] = *(const ushort4*)(hs + (size_t)idx[i] * 128 + c4g);
                #pragma unroll
                for (int i = 0; i < 8; i += 2){
                    ax0 += bf2f(v[i].x); ax1 += bf2f(v[i + 1].x);
                    ay0 += bf2f(v[i].y); ay1 += bf2f(v[i + 1].y);
                    az0 += bf2f(v[i].z); az1 += bf2f(v[i + 1].z);
                    aw0 += bf2f(v[i].w); aw1 += bf2f(v[i + 1].w);
                }
            }
            for (; e < cnt; e++){
                ushort4 v = *(const ushort4*)(hs + (size_t)csr[off + e] * 128 + c4g);
                ax0 += bf2f(v.x); ay0 += bf2f(v.y); az0 += bf2f(v.z); aw0 += bf2f(v.w);
            }
            float dv = dinv[node];
            float4 r;
            r.x = dv * (ax0 + ax1); r.y = dv * (ay0 + ay1);
            r.z = dv * (az0 + az1); r.w = dv * (aw0 + aw1);
            *(float4*)&a2t[nl * 128 + c4g] = r;
        }
    }
    __syncthreads();
    // --- phase B: out[rows] = a2t[rows] @ W2 + b2 ; 4 rows x 4 cols/thread ---
    int c4 = lane * 4;                 // output col base
    int r0 = (threadIdx.x >> 5) * 4;   // 4 local rows
    float4 bias = *(const float4*)(b2 + c4);
    float4 acc0 = bias, acc1 = bias, acc2 = bias, acc3 = bias;
    for (int k = 0; k < 128; k += 4){
        float4 a0  = *(const float4*)&a2t[(r0 + 0) * 128 + k];
        float4 a1v = *(const float4*)&a2t[(r0 + 1) * 128 + k];
        float4 a2v = *(const float4*)&a2t[(r0 + 2) * 128 + k];
        float4 a3v = *(const float4*)&a2t[(r0 + 3) * 128 + k];
        #pragma unroll
        for (int kk = 0; kk < 4; kk++){
            float4 wv = *(const float4*)(W2 + (size_t)(k + kk) * 128 + c4);
            float b0 = (kk == 0) ? a0.x  : (kk == 1) ? a0.y  : (kk == 2) ? a0.z  : a0.w;
            float b1v= (kk == 0) ? a1v.x : (kk == 1) ? a1v.y : (kk == 2) ? a1v.z : a1v.w;
            float b2v= (kk == 0) ? a2v.x : (kk == 1) ? a2v.y : (kk == 2) ? a2v.z : a2v.w;
            float b3 = (kk == 0) ? a3v.x : (kk == 1) ? a3v.y : (kk == 2) ? a3v.z : a3v.w;
            acc0.x += b0 * wv.x; acc0.y += b0 * wv.y; acc0.z += b0 * wv.z; acc0.w += b0 * wv.w;
            acc1.x += b1v * wv.x; acc1.y += b1v * wv.y; acc1.z += b1v * wv.z; acc1.w += b1v * wv.w;
            acc2.x += b2v * wv.x; acc2.y += b2v * wv.y; acc2.z += b2v * wv.z; acc2.w += b2v * wv.w;
            acc3.x += b3 * wv.x; acc3.y += b3 * wv.y; acc3.z += b3 * wv.z; acc3.w += b3 * wv.w;
        }
    }
    int rb = blockIdx.x * 32 + r0;
    if (rb + 0 < n) nt_store4(out + (size_t)(rb + 0) * 128 + c4, acc0);
    if (rb + 1 < n) nt_store4(out + (size_t)(rb + 1) * 128 + c4, acc1);
    if (rb + 2 < n) nt_store4(out + (size_t)(rb + 2) * 128 + c4, acc2);
    if (rb + 3 < n) nt_store4(out + (size_t)(rb + 3) * 128 + c4, acc3);
}

extern "C" void kernel_launch(void* const* d_in, const int* in_sizes, int n_in,
                              void* d_out, int out_size, void* d_ws, size_t ws_size,
                              hipStream_t stream){
    const int*   x    = (const int*)d_in[0];
    const int*   ei   = (const int*)d_in[1];
    const float* emb  = (const float*)d_in[2];
    const float* W1   = (const float*)d_in[3];
    const float* b1   = (const float*)d_in[4];
    const float* W2   = (const float*)d_in[5];
    const float* b2   = (const float*)d_in[6];
    const int N = in_sizes[0];
    const int E = in_sizes[1] / 2;
    const int* srcv = ei;
    const int* dstv = ei + E;
    float* out = (float*)d_out;

    char* p = (char*)d_ws;
    auto alloc = [&](size_t bytes) -> char* {
        char* r = p; p += (bytes + 255) & ~(size_t)255; return r;
    };
    int nb = cdiv(N, 256);
    int*            ecount  = (int*)           alloc((size_t)(N + 8) * 4); // +8: gcur
    int*            gcur    = ecount + N;
    int*            offsets = (int*)           alloc((size_t)N * 4);
    int*            bsum    = (int*)           alloc((size_t)nb * 4);
    float*          dinv    = (float*)         alloc((size_t)N * 4);
    int*            csr     = (int*)           alloc((size_t)E * 4);
    unsigned short* es      = (unsigned short*)alloc((size_t)N * 32 * 2);
    int*            H       = (int*)           alloc((size_t)8 * NC * NPP * 4); // 6.4 MB
    unsigned short* hs      = (unsigned short*)alloc((size_t)N * 128 * 2);
    int*            staged  = (int*)           alloc((size_t)(E + 8 * 65536) * 4);
    (void)ws_size; (void)n_in; (void)out_size;

    const int npp = cdiv(N, 8);          // nodes per partition (== NPP for N=50000)
    const int C   = E / 8 + 65536;       // staged capacity per partition
    const int CH  = cdiv(C, NC);         // edges per chunk

    // --- CSR build (no global atomics on hot path) ---
    k_zero_i32<<<1, 64, 0, stream>>>(gcur, 8);
    k_bucket  <<<cdiv(E, 1024), 256, 0, stream>>>(srcv, dstv, E, staged, gcur, npp, C);
    k_hist    <<<8 * NC, 256, 0, stream>>>(staged, gcur, C, CH, npp, H);
    k_nodescan<<<nb, 256, 0, stream>>>(H, npp, N, ecount, dinv, bsum);
    k_scanBC  <<<nb, 256, 0, stream>>>(ecount, N, bsum, nb, offsets);
    k_fill3   <<<8 * NC, 256, 0, stream>>>(staged, gcur, C, CH, npp, H, offsets, csr);

    // --- layer 1 (fused): scale -> [gather+GEMM] -> hs ---
    k_scale <<<cdiv(N * 32, 256), 256, 0, stream>>>(emb, x, dinv, es, N);
    k_l1    <<<cdiv(N, 8), 256, 0, stream>>>(es, offsets, ecount, csr, dinv, W1, b1, hs, N);

    // --- layer 2 (fused): [gather+GEMM] -> out ---
    k_l2    <<<cdiv(N, 32), 256, 0, stream>>>(hs, offsets, ecount, csr, dinv, W2, b2, out, N);
}